// Round 13
// baseline (281.755 us; speedup 1.0000x reference)
//
#include <hip/hip_runtime.h>
#include <hip/hip_bf16.h>
#include <cstdint>
#include <cstddef>

#define NEG_SLOPE 0.01f

static __device__ __forceinline__ unsigned short f2bf(float f) {
    __hip_bfloat16 b = __float2bfloat16(f);   // RNE
    return *(unsigned short*)&b;
}
static __device__ __forceinline__ float bf2f(unsigned short u) {
    __hip_bfloat16 b = *(__hip_bfloat16*)&u;
    return __bfloat162float(b);
}

// ============================================================================
// Layer-1 GEMM: z1 = feature[N,128] @ W1[128,32] (bf16 out) + fp32 logits.
// ============================================================================

__global__ __launch_bounds__(128) void gemm1_kernel(
    const float* __restrict__ h, const float* __restrict__ W,
    const float* __restrict__ a, unsigned short* __restrict__ zb,
    float* __restrict__ s_src, float* __restrict__ s_dst, int N)
{
    __shared__ float Wl[128 * 32];
    int tid = threadIdx.x;
    int rowBase = blockIdx.x * 64;

    {
        const float4* W4 = (const float4*)W;
        float4* Wl4 = (float4*)Wl;
        for (int i = tid; i < 1024; i += 128) Wl4[i] = W4[i];
    }
    __syncthreads();

    int wv   = tid >> 6;
    int lane = tid & 63;
    int g    = lane >> 3;
    int l8   = lane & 7;
    int r0   = wv * 32 + g * 4;
    int col4 = l8 * 4;

    float acc[4][4];
#pragma unroll
    for (int i = 0; i < 4; i++)
#pragma unroll
        for (int c = 0; c < 4; c++) acc[i][c] = 0.f;

    const float4* h4  = (const float4*)h;
    const float4* Wl4 = (const float4*)Wl;

    size_t rowOff[4];
#pragma unroll
    for (int i = 0; i < 4; i++) {
        int r = rowBase + r0 + i;
        rowOff[i] = (size_t)((r < N) ? r : (N - 1)) * 32;
    }

#pragma unroll 2
    for (int kq = 0; kq < 32; kq++) {
        float4 w0 = Wl4[(kq * 4 + 0) * 8 + l8];
        float4 w1 = Wl4[(kq * 4 + 1) * 8 + l8];
        float4 w2 = Wl4[(kq * 4 + 2) * 8 + l8];
        float4 w3 = Wl4[(kq * 4 + 3) * 8 + l8];
#pragma unroll
        for (int i = 0; i < 4; i++) {
            float4 hv = h4[rowOff[i] + kq];
            acc[i][0] += hv.x * w0.x; acc[i][1] += hv.x * w0.y;
            acc[i][2] += hv.x * w0.z; acc[i][3] += hv.x * w0.w;
            acc[i][0] += hv.y * w1.x; acc[i][1] += hv.y * w1.y;
            acc[i][2] += hv.y * w1.z; acc[i][3] += hv.y * w1.w;
            acc[i][0] += hv.z * w2.x; acc[i][1] += hv.z * w2.y;
            acc[i][2] += hv.z * w2.z; acc[i][3] += hv.z * w2.w;
            acc[i][0] += hv.w * w3.x; acc[i][1] += hv.w * w3.y;
            acc[i][2] += hv.w * w3.z; acc[i][3] += hv.w * w3.w;
        }
    }

    float4 alo = ((const float4*)a)[l8];
    float4 ahi = ((const float4*)a)[8 + l8];
#pragma unroll
    for (int i = 0; i < 4; i++) {
        int row = rowBase + r0 + i;
        if (row < N) {
            ushort4 zv4 = make_ushort4(f2bf(acc[i][0]), f2bf(acc[i][1]),
                                       f2bf(acc[i][2]), f2bf(acc[i][3]));
            *(ushort4*)&zb[(size_t)row * 32 + col4] = zv4;
            float ps = acc[i][0] * alo.x + acc[i][1] * alo.y + acc[i][2] * alo.z + acc[i][3] * alo.w;
            float pd = acc[i][0] * ahi.x + acc[i][1] * ahi.y + acc[i][2] * ahi.z + acc[i][3] * ahi.w;
            ps += __shfl_xor(ps, 1, 64); ps += __shfl_xor(ps, 2, 64); ps += __shfl_xor(ps, 4, 64);
            pd += __shfl_xor(pd, 1, 64); pd += __shfl_xor(pd, 2, 64); pd += __shfl_xor(pd, 4, 64);
            if (l8 == 0) { s_src[row] = ps; s_dst[row] = pd; }
        }
    }
}

// ============================================================================
// Atomic-free CSR build: two-level counting sort by dst (LDS atomics only).
// ============================================================================

#define TILE_E 4096
#define NB_MAX 512     // supports N <= 131072

__global__ __launch_bounds__(256) void csr_hist_kernel(
    const int* __restrict__ dst, int* __restrict__ counts,
    int E, int TB, int NB)
{
    __shared__ int hist[NB_MAX];
    int tid = threadIdx.x;
    int t = blockIdx.x;
    for (int b = tid; b < NB; b += 256) hist[b] = 0;
    __syncthreads();
    int base = t * TILE_E;
    for (int i = tid; i < TILE_E; i += 256) {
        int k = base + i;
        if (k < E) atomicAdd(&hist[dst[k] >> 8], 1);
    }
    __syncthreads();
    for (int b = tid; b < NB; b += 256) counts[b * TB + t] = hist[b];
}

__global__ __launch_bounds__(256) void scan1_kernel(
    const int* __restrict__ vals, int* __restrict__ incl,
    int* __restrict__ blockSums, int M)
{
    __shared__ int tmp[256];
    int tid = threadIdx.x;
    int i = blockIdx.x * 256 + tid;
    int v = (i < M) ? vals[i] : 0;
    tmp[tid] = v;
    __syncthreads();
#pragma unroll
    for (int off = 1; off < 256; off <<= 1) {
        int t = (tid >= off) ? tmp[tid - off] : 0;
        __syncthreads();
        tmp[tid] += t;
        __syncthreads();
    }
    if (i < M) incl[i] = tmp[tid];
    if (tid == 255) blockSums[blockIdx.x] = tmp[255];
}

__global__ __launch_bounds__(1024) void scan2_kernel(int* __restrict__ blockSums, int nb)
{
    __shared__ int tmp[1024];
    int tid = threadIdx.x;
    int v = (tid < nb) ? blockSums[tid] : 0;
    tmp[tid] = v;
    __syncthreads();
#pragma unroll
    for (int off = 1; off < 1024; off <<= 1) {
        int t = (tid >= off) ? tmp[tid - off] : 0;
        __syncthreads();
        tmp[tid] += t;
        __syncthreads();
    }
    if (tid < nb) blockSums[tid] = tmp[tid] - v;  // exclusive
}

__global__ __launch_bounds__(256) void scan3_kernel(
    const int* __restrict__ vals, const int* __restrict__ blockSums,
    int* __restrict__ cscan, int M, int E)
{
    int i = blockIdx.x * 256 + threadIdx.x;
    if (i < M) {
        cscan[i] = cscan[i] - vals[i] + blockSums[i >> 8];
    }
    if (i == 0) cscan[M] = E;
}

__global__ __launch_bounds__(256) void csr_scatter_kernel(
    const int* __restrict__ src, const int* __restrict__ dst,
    const int* __restrict__ cscan, int* __restrict__ ebuf,
    int E, int TB, int NB)
{
    __shared__ int baseB[NB_MAX];
    __shared__ int cur[NB_MAX];
    int tid = threadIdx.x;
    int t = blockIdx.x;
    for (int b = tid; b < NB; b += 256) {
        baseB[b] = cscan[b * TB + t];
        cur[b] = 0;
    }
    __syncthreads();
    int base = t * TILE_E;
    for (int i = tid; i < TILE_E; i += 256) {
        int k = base + i;
        if (k < E) {
            int d = dst[k], s = src[k];
            int b = d >> 8;
            int r = atomicAdd(&cur[b], 1);
            ebuf[baseB[b] + r] = (s << 8) | (d & 255);
        }
    }
}

__global__ __launch_bounds__(256) void csr_bucket_kernel(
    const int* __restrict__ ebuf, const int* __restrict__ cscan,
    int* __restrict__ csr_src, int* __restrict__ offsets,
    int N, int E, int TB)
{
    __shared__ int eb[8192];      // 32KB staging
    __shared__ int hist[256];
    __shared__ int loff[256];
    __shared__ int tmp[256];
    int tid = threadIdx.x;
    int b = blockIdx.x;

    int beg = cscan[b * TB];
    int endv = cscan[(b + 1) * TB];
    int cnt = endv - beg;
    int first = b << 8;

    hist[tid] = 0;
    __syncthreads();

    bool inLds = (cnt <= 8192);
    for (int i = tid; i < cnt; i += 256) {
        int v = ebuf[beg + i];
        if (inLds) eb[i] = v;
        atomicAdd(&hist[v & 255], 1);
    }
    __syncthreads();

    int hv = hist[tid];
    tmp[tid] = hv;
    __syncthreads();
#pragma unroll
    for (int off = 1; off < 256; off <<= 1) {
        int t = (tid >= off) ? tmp[tid - off] : 0;
        __syncthreads();
        tmp[tid] += t;
        __syncthreads();
    }
    loff[tid] = tmp[tid] - hv;
    __syncthreads();

    if (first + tid < N) offsets[first + tid] = beg + loff[tid];
    if (b == 0 && tid == 0) offsets[N] = E;

    hist[tid] = 0;
    __syncthreads();

    for (int i = tid; i < cnt; i += 256) {
        int v = inLds ? eb[i] : ebuf[beg + i];
        int d8 = v & 255;
        int r = atomicAdd(&hist[d8], 1);
        csr_src[beg + loff[d8] + r] = v >> 8;
    }
}

// ============================================================================
// Gather core: fused softmax + weighted bf16 aggregation, one node per
// 32-lane group. Produces v = relu(sum(alpha*z)).
// ============================================================================

#define AGG32_CORE(S_SRC, S_DST, ZB)                                          \
    int beg = offsets[node], end = offsets[node + 1];                         \
    int deg = end - beg;                                                      \
    float sd = (S_DST)[node];                                                 \
    float o = 0.f;                                                            \
    float rden;                                                               \
    if (deg <= 128) {                                                         \
        int   sreg[4];                                                        \
        float ev[4];                                                          \
        int nIter = (deg + 31) >> 5;                                          \
        float m = -3.0e38f;                                                   \
        _Pragma("unroll 4")                                                   \
        for (int it = 0; it < nIter; ++it) {                                  \
            int p = beg + it * 32 + lane;                                     \
            float e = -3.0e38f;                                               \
            int s = 0;                                                        \
            if (p < end) {                                                    \
                s = csr_src[p];                                               \
                e = (S_SRC)[s] + sd;                                          \
                e = (e > 0.f) ? e : NEG_SLOPE * e;                            \
            }                                                                 \
            sreg[it] = s;                                                     \
            ev[it] = e;                                                       \
            m = fmaxf(m, e);                                                  \
        }                                                                     \
        _Pragma("unroll")                                                     \
        for (int off = 16; off > 0; off >>= 1)                                \
            m = fmaxf(m, __shfl_xor(m, off, 32));                             \
        float l = 0.f;                                                        \
        _Pragma("unroll 4")                                                   \
        for (int it = 0; it < nIter; ++it) {                                  \
            int p = beg + it * 32 + lane;                                     \
            float w = (p < end) ? __expf(ev[it] - m) : 0.f;                   \
            ws[it * 32 + lane] = make_float2(w, __int_as_float(sreg[it]));    \
            l += w;                                                           \
        }                                                                     \
        _Pragma("unroll")                                                     \
        for (int off = 16; off > 0; off >>= 1) l += __shfl_xor(l, off, 32);   \
        rden = 1.f / fmaxf(l, 1e-9f);                                         \
        int p = 0;                                                            \
        for (; p + 8 <= deg; p += 8) {                                        \
            float2 a0 = ws[p],     a1 = ws[p + 1];                            \
            float2 a2 = ws[p + 2], a3 = ws[p + 3];                            \
            float2 a4 = ws[p + 4], a5 = ws[p + 5];                            \
            float2 a6 = ws[p + 6], a7 = ws[p + 7];                            \
            unsigned short u0 = (ZB)[(size_t)__float_as_int(a0.y) * 32 + lane]; \
            unsigned short u1 = (ZB)[(size_t)__float_as_int(a1.y) * 32 + lane]; \
            unsigned short u2 = (ZB)[(size_t)__float_as_int(a2.y) * 32 + lane]; \
            unsigned short u3 = (ZB)[(size_t)__float_as_int(a3.y) * 32 + lane]; \
            unsigned short u4 = (ZB)[(size_t)__float_as_int(a4.y) * 32 + lane]; \
            unsigned short u5 = (ZB)[(size_t)__float_as_int(a5.y) * 32 + lane]; \
            unsigned short u6 = (ZB)[(size_t)__float_as_int(a6.y) * 32 + lane]; \
            unsigned short u7 = (ZB)[(size_t)__float_as_int(a7.y) * 32 + lane]; \
            o += a0.x * bf2f(u0); o += a1.x * bf2f(u1);                       \
            o += a2.x * bf2f(u2); o += a3.x * bf2f(u3);                       \
            o += a4.x * bf2f(u4); o += a5.x * bf2f(u5);                       \
            o += a6.x * bf2f(u6); o += a7.x * bf2f(u7);                       \
        }                                                                     \
        for (; p < deg; ++p) {                                                \
            float2 aa = ws[p];                                                \
            o += aa.x * bf2f((ZB)[(size_t)__float_as_int(aa.y) * 32 + lane]); \
        }                                                                     \
    } else {                                                                  \
        float m = -3.0e38f;                                                   \
        for (int p = beg + lane; p < end; p += 32) {                          \
            float e = (S_SRC)[csr_src[p]] + sd;                               \
            e = (e > 0.f) ? e : NEG_SLOPE * e;                                \
            m = fmaxf(m, e);                                                  \
        }                                                                     \
        _Pragma("unroll")                                                     \
        for (int off = 16; off > 0; off >>= 1)                                \
            m = fmaxf(m, __shfl_xor(m, off, 32));                             \
        float l = 0.f;                                                        \
        for (int p = beg + lane; p < end; p += 32) {                          \
            float e = (S_SRC)[csr_src[p]] + sd;                               \
            e = (e > 0.f) ? e : NEG_SLOPE * e;                                \
            l += __expf(e - m);                                               \
        }                                                                     \
        _Pragma("unroll")                                                     \
        for (int off = 16; off > 0; off >>= 1) l += __shfl_xor(l, off, 32);   \
        rden = 1.f / fmaxf(l, 1e-9f);                                         \
        for (int p = beg; p < end; ++p) {                                     \
            int s = csr_src[p];                                               \
            float e = (S_SRC)[s] + sd;                                        \
            e = (e > 0.f) ? e : NEG_SLOPE * e;                                \
            float w = __expf(e - m);                                          \
            o += w * bf2f((ZB)[(size_t)s * 32 + lane]);                       \
        }                                                                     \
    }                                                                         \
    float v = o * rden;                                                       \
    v = (v > 0.f) ? v : 0.f;   /* relu */

// ---- layer 1 agg, fused gemm2 epilogue (R12 fix: the 32-shfl matvec cost
// ~30us of LDS pipe; now W2 column lives in 32 VGPRs/lane, h is broadcast
// back via 1 ds_write + 8 ds_read_b128 -> 9 LDS ops/node instead of 64) ----
__global__ __launch_bounds__(256) void agg32_l1_kernel(
    const int* __restrict__ offsets, const int* __restrict__ csr_src,
    const float* __restrict__ s_src1, const float* __restrict__ s_dst1,
    const unsigned short* __restrict__ zb1,
    const float* __restrict__ W2, const float* __restrict__ a2,
    unsigned short* __restrict__ zb2,
    float* __restrict__ s_src2, float* __restrict__ s_dst2, int N)
{
    __shared__ float W2l[32 * 32];      // 4 KB (stage once per block)
    __shared__ float2 wsbuf[8 * 128];   // 8 KB
    __shared__ float hl[8 * 32];        // 1 KB: per-group h row
    int tid = threadIdx.x;
    for (int i = tid; i < 1024; i += 256) W2l[i] = W2[i];
    __syncthreads();

    int g    = tid >> 5;
    int lane = tid & 31;

    // per-block: pull this lane's W2 column into registers (amortized 4/node)
    float w2c[32];
#pragma unroll
    for (int k = 0; k < 32; ++k) w2c[k] = W2l[k * 32 + lane];

    int node = blockIdx.x * 8 + g;
    if (node >= N) return;
    float2* ws = &wsbuf[g * 128];

    AGG32_CORE(s_src1, s_dst1, zb1)

    // fused gemm2: z2[node][lane] = sum_k h1[k] * W2[k][lane]
    hl[g * 32 + lane] = v;              // intra-wave: no barrier needed
    const float4* hb4 = (const float4*)&hl[g * 32];
    float acc2 = 0.f;
#pragma unroll
    for (int c = 0; c < 8; ++c) {
        float4 hv = hb4[c];             // same-addr broadcast, conflict-free
        acc2 += hv.x * w2c[c * 4 + 0] + hv.y * w2c[c * 4 + 1]
              + hv.z * w2c[c * 4 + 2] + hv.w * w2c[c * 4 + 3];
    }

    zb2[(size_t)node * 32 + lane] = f2bf(acc2);
    float ps = acc2 * a2[lane];
    float pd = acc2 * a2[32 + lane];
#pragma unroll
    for (int off = 16; off > 0; off >>= 1) {
        ps += __shfl_xor(ps, off, 32);
        pd += __shfl_xor(pd, off, 32);
    }
    if (lane == 0) { s_src2[node] = ps; s_dst2[node] = pd; }
}

// ---- layer 2 agg, fused gemm3 epilogue: emits zs={z3,z3*a0}, s_dst3 ----
__global__ __launch_bounds__(256) void agg32_l2_kernel(
    const int* __restrict__ offsets, const int* __restrict__ csr_src,
    const float* __restrict__ s_src2, const float* __restrict__ s_dst2,
    const unsigned short* __restrict__ zb2,
    const float* __restrict__ W3, const float* __restrict__ a3,
    float2* __restrict__ zs, float* __restrict__ s_dst3, int N)
{
    __shared__ float2 wsbuf[8 * 128];
    int tid  = threadIdx.x;
    int g    = tid >> 5;
    int lane = tid & 31;
    int node = blockIdx.x * 8 + g;
    if (node >= N) return;
    float2* ws = &wsbuf[g * 128];
    float w3 = W3[lane];

    AGG32_CORE(s_src2, s_dst2, zb2)

    // fused gemm3: z3 = sum_lane h2[lane] * W3[lane]
    float t = v * w3;
#pragma unroll
    for (int off = 16; off > 0; off >>= 1) t += __shfl_xor(t, off, 32);
    if (lane == 0) {
        zs[node] = make_float2(t, t * a3[0]);
        s_dst3[node] = t * a3[1];
    }
}

// ---- layer 3: fully edge-parallel, one 8B fp32 gather per edge, sigmoid ----
__global__ __launch_bounds__(256) void agg1_fused_kernel(
    const int* __restrict__ offsets, const int* __restrict__ csr_src,
    const float2* __restrict__ zs, const float* __restrict__ s_dst,
    float* __restrict__ out, int N)
{
    int node = blockIdx.x * 8 + (threadIdx.x >> 5);
    int lane = threadIdx.x & 31;
    if (node >= N) return;

    int beg = offsets[node], end = offsets[node + 1];
    int deg = end - beg;
    float sd = s_dst[node];

    if (deg <= 128) {
        float ev[4], zv[4];
        int nIter = (deg + 31) >> 5;
        float m = -3.0e38f;
#pragma unroll 4
        for (int it = 0; it < nIter; ++it) {
            int p = beg + it * 32 + lane;
            float e = -3.0e38f, zz = 0.f;
            if (p < end) {
                float2 v2 = zs[csr_src[p]];
                zz = v2.x;
                e = v2.y + sd;
                e = (e > 0.f) ? e : NEG_SLOPE * e;
            }
            ev[it] = e; zv[it] = zz;
            m = fmaxf(m, e);
        }
#pragma unroll
        for (int off = 16; off > 0; off >>= 1) m = fmaxf(m, __shfl_xor(m, off, 32));
        float l = 0.f, o = 0.f;
#pragma unroll 4
        for (int it = 0; it < nIter; ++it) {
            int p = beg + it * 32 + lane;
            float w = (p < end) ? __expf(ev[it] - m) : 0.f;
            l += w;
            o += w * zv[it];
        }
#pragma unroll
        for (int off = 16; off > 0; off >>= 1) {
            l += __shfl_xor(l, off, 32);
            o += __shfl_xor(o, off, 32);
        }
        if (lane == 0) {
            float v = o / fmaxf(l, 1e-9f);
            out[node] = 1.f / (1.f + __expf(-v));
        }
    } else {
        float m = -3.0e38f;
        for (int p = beg + lane; p < end; p += 32) {
            float e = zs[csr_src[p]].y + sd;
            e = (e > 0.f) ? e : NEG_SLOPE * e;
            m = fmaxf(m, e);
        }
#pragma unroll
        for (int off = 16; off > 0; off >>= 1) m = fmaxf(m, __shfl_xor(m, off, 32));
        float l = 0.f, o = 0.f;
        for (int p = beg + lane; p < end; p += 32) {
            float2 v2 = zs[csr_src[p]];
            float e = v2.y + sd;
            e = (e > 0.f) ? e : NEG_SLOPE * e;
            float w = __expf(e - m);
            l += w; o += w * v2.x;
        }
#pragma unroll
        for (int off = 16; off > 0; off >>= 1) {
            l += __shfl_xor(l, off, 32);
            o += __shfl_xor(o, off, 32);
        }
        if (lane == 0) {
            float v = o / fmaxf(l, 1e-9f);
            out[node] = 1.f / (1.f + __expf(-v));
        }
    }
}

// ============================================================================

extern "C" void kernel_launch(void* const* d_in, const int* in_sizes, int n_in,
                              void* d_out, int out_size, void* d_ws, size_t ws_size,
                              hipStream_t stream)
{
    const float* feature = (const float*)d_in[0];
    const int*   src     = (const int*)d_in[1];
    const int*   dst     = (const int*)d_in[2];
    const float* W1      = (const float*)d_in[3];
    const float* a1      = (const float*)d_in[4];
    const float* W2      = (const float*)d_in[5];
    const float* a2      = (const float*)d_in[6];
    const float* W3      = (const float*)d_in[7];
    const float* a3      = (const float*)d_in[8];
    float* out = (float*)d_out;

    const int N = in_sizes[0] / 128;
    const int E = in_sizes[1];

    const int TB = (E + TILE_E - 1) / TILE_E;
    const int NB = (N + 255) >> 8;
    const int M  = NB * TB;

    // ---- workspace layout ----
    char* p = (char*)d_ws;
    unsigned short* zb1 = (unsigned short*)p;  p += (size_t)N * 32 * sizeof(unsigned short);
    unsigned short* zb2 = (unsigned short*)p;  p += (size_t)N * 32 * sizeof(unsigned short);
    float* zs32    = (float*)p;  p += (size_t)N * 2 * sizeof(float);
    float* s_src1  = (float*)p;  p += (size_t)N * sizeof(float);
    float* s_dst1  = (float*)p;  p += (size_t)N * sizeof(float);
    float* s_src2  = (float*)p;  p += (size_t)N * sizeof(float);
    float* s_dst2  = (float*)p;  p += (size_t)N * sizeof(float);
    float* s_dst3  = (float*)p;  p += (size_t)N * sizeof(float);
    int*   offsets = (int*)p;    p += ((size_t)N + 1) * sizeof(int);
    int*   counts  = (int*)p;    p += ((size_t)M + 1) * sizeof(int);
    int*   cscan   = (int*)p;    p += ((size_t)M + 1) * sizeof(int);
    int*   blockSums = (int*)p;  p += 1024 * sizeof(int);
    int*   ebuf    = (int*)p;    p += (size_t)E * sizeof(int);
    int*   csr_src = (int*)p;    p += (size_t)E * sizeof(int);

    const int nodeBlocks8  = (N + 7) / 8;
    const int gemmBlocks64 = (N + 63) / 64;
    const int scanBlocksM  = (M + 255) / 256;

    // ---- build CSR: atomic-free two-level counting sort ----
    hipLaunchKernelGGL(csr_hist_kernel, dim3(TB), dim3(256), 0, stream,
                       dst, counts, E, TB, NB);
    hipLaunchKernelGGL(scan1_kernel, dim3(scanBlocksM), dim3(256), 0, stream,
                       counts, cscan, blockSums, M);
    hipLaunchKernelGGL(scan2_kernel, dim3(1), dim3(1024), 0, stream,
                       blockSums, scanBlocksM);
    hipLaunchKernelGGL(scan3_kernel, dim3(scanBlocksM), dim3(256), 0, stream,
                       counts, blockSums, cscan, M, E);
    hipLaunchKernelGGL(csr_scatter_kernel, dim3(TB), dim3(256), 0, stream,
                       src, dst, cscan, ebuf, E, TB, NB);
    hipLaunchKernelGGL(csr_bucket_kernel, dim3(NB), dim3(256), 0, stream,
                       ebuf, cscan, csr_src, offsets, N, E, TB);

    // ---- layer 1: gemm1 -> z1; agg(l1) fused with gemm2 -> z2 ----
    hipLaunchKernelGGL(gemm1_kernel, dim3(gemmBlocks64), dim3(128), 0, stream,
                       feature, W1, a1, zb1, s_src1, s_dst1, N);
    hipLaunchKernelGGL(agg32_l1_kernel, dim3(nodeBlocks8), dim3(256), 0, stream,
                       offsets, csr_src, s_src1, s_dst1, zb1, W2, a2,
                       zb2, s_src2, s_dst2, N);

    // ---- layer 2: agg(l2) fused with gemm3 -> zs, s_dst3 ----
    float2* zs = (float2*)zs32;
    hipLaunchKernelGGL(agg32_l2_kernel, dim3(nodeBlocks8), dim3(256), 0, stream,
                       offsets, csr_src, s_src2, s_dst2, zb2, W3, a3,
                       zs, s_dst3, N);

    // ---- layer 3: edge-parallel agg + sigmoid ----
    hipLaunchKernelGGL(agg1_fused_kernel, dim3(nodeBlocks8), dim3(256), 0, stream,
                       offsets, csr_src, zs, s_dst3, out, N);
}

// Round 14
// 266.691 us; speedup vs baseline: 1.0565x; 1.0565x over previous
//
#include <hip/hip_runtime.h>
#include <hip/hip_bf16.h>
#include <cstdint>
#include <cstddef>

#define NEG_SLOPE 0.01f

static __device__ __forceinline__ unsigned short f2bf(float f) {
    __hip_bfloat16 b = __float2bfloat16(f);   // RNE
    return *(unsigned short*)&b;
}
static __device__ __forceinline__ float bf2f(unsigned short u) {
    __hip_bfloat16 b = *(__hip_bfloat16*)&u;
    return __bfloat162float(b);
}

// ============================================================================
// Layer-1 GEMM: z1 = feature[N,128] @ W1[128,32] (bf16 out) + fp32 logits.
// ============================================================================

__global__ __launch_bounds__(128) void gemm1_kernel(
    const float* __restrict__ h, const float* __restrict__ W,
    const float* __restrict__ a, unsigned short* __restrict__ zb,
    float* __restrict__ s_src, float* __restrict__ s_dst, int N)
{
    __shared__ float Wl[128 * 32];
    int tid = threadIdx.x;
    int rowBase = blockIdx.x * 64;

    {
        const float4* W4 = (const float4*)W;
        float4* Wl4 = (float4*)Wl;
        for (int i = tid; i < 1024; i += 128) Wl4[i] = W4[i];
    }
    __syncthreads();

    int wv   = tid >> 6;
    int lane = tid & 63;
    int g    = lane >> 3;
    int l8   = lane & 7;
    int r0   = wv * 32 + g * 4;
    int col4 = l8 * 4;

    float acc[4][4];
#pragma unroll
    for (int i = 0; i < 4; i++)
#pragma unroll
        for (int c = 0; c < 4; c++) acc[i][c] = 0.f;

    const float4* h4  = (const float4*)h;
    const float4* Wl4 = (const float4*)Wl;

    size_t rowOff[4];
#pragma unroll
    for (int i = 0; i < 4; i++) {
        int r = rowBase + r0 + i;
        rowOff[i] = (size_t)((r < N) ? r : (N - 1)) * 32;
    }

#pragma unroll 2
    for (int kq = 0; kq < 32; kq++) {
        float4 w0 = Wl4[(kq * 4 + 0) * 8 + l8];
        float4 w1 = Wl4[(kq * 4 + 1) * 8 + l8];
        float4 w2 = Wl4[(kq * 4 + 2) * 8 + l8];
        float4 w3 = Wl4[(kq * 4 + 3) * 8 + l8];
#pragma unroll
        for (int i = 0; i < 4; i++) {
            float4 hv = h4[rowOff[i] + kq];
            acc[i][0] += hv.x * w0.x; acc[i][1] += hv.x * w0.y;
            acc[i][2] += hv.x * w0.z; acc[i][3] += hv.x * w0.w;
            acc[i][0] += hv.y * w1.x; acc[i][1] += hv.y * w1.y;
            acc[i][2] += hv.y * w1.z; acc[i][3] += hv.y * w1.w;
            acc[i][0] += hv.z * w2.x; acc[i][1] += hv.z * w2.y;
            acc[i][2] += hv.z * w2.z; acc[i][3] += hv.z * w2.w;
            acc[i][0] += hv.w * w3.x; acc[i][1] += hv.w * w3.y;
            acc[i][2] += hv.w * w3.z; acc[i][3] += hv.w * w3.w;
        }
    }

    float4 alo = ((const float4*)a)[l8];
    float4 ahi = ((const float4*)a)[8 + l8];
#pragma unroll
    for (int i = 0; i < 4; i++) {
        int row = rowBase + r0 + i;
        if (row < N) {
            ushort4 zv4 = make_ushort4(f2bf(acc[i][0]), f2bf(acc[i][1]),
                                       f2bf(acc[i][2]), f2bf(acc[i][3]));
            *(ushort4*)&zb[(size_t)row * 32 + col4] = zv4;
            float ps = acc[i][0] * alo.x + acc[i][1] * alo.y + acc[i][2] * alo.z + acc[i][3] * alo.w;
            float pd = acc[i][0] * ahi.x + acc[i][1] * ahi.y + acc[i][2] * ahi.z + acc[i][3] * ahi.w;
            ps += __shfl_xor(ps, 1, 64); ps += __shfl_xor(ps, 2, 64); ps += __shfl_xor(ps, 4, 64);
            pd += __shfl_xor(pd, 1, 64); pd += __shfl_xor(pd, 2, 64); pd += __shfl_xor(pd, 4, 64);
            if (l8 == 0) { s_src[row] = ps; s_dst[row] = pd; }
        }
    }
}

// ============================================================================
// Atomic-free CSR build: two-level counting sort by dst (LDS atomics only).
// ============================================================================

#define TILE_E 4096
#define NB_MAX 512     // supports N <= 131072

__global__ __launch_bounds__(256) void csr_hist_kernel(
    const int* __restrict__ dst, int* __restrict__ counts,
    int E, int TB, int NB)
{
    __shared__ int hist[NB_MAX];
    int tid = threadIdx.x;
    int t = blockIdx.x;
    for (int b = tid; b < NB; b += 256) hist[b] = 0;
    __syncthreads();
    int base = t * TILE_E;
    for (int i = tid; i < TILE_E; i += 256) {
        int k = base + i;
        if (k < E) atomicAdd(&hist[dst[k] >> 8], 1);
    }
    __syncthreads();
    for (int b = tid; b < NB; b += 256) counts[b * TB + t] = hist[b];
}

__global__ __launch_bounds__(256) void scan1_kernel(
    const int* __restrict__ vals, int* __restrict__ incl,
    int* __restrict__ blockSums, int M)
{
    __shared__ int tmp[256];
    int tid = threadIdx.x;
    int i = blockIdx.x * 256 + tid;
    int v = (i < M) ? vals[i] : 0;
    tmp[tid] = v;
    __syncthreads();
#pragma unroll
    for (int off = 1; off < 256; off <<= 1) {
        int t = (tid >= off) ? tmp[tid - off] : 0;
        __syncthreads();
        tmp[tid] += t;
        __syncthreads();
    }
    if (i < M) incl[i] = tmp[tid];
    if (tid == 255) blockSums[blockIdx.x] = tmp[255];
}

__global__ __launch_bounds__(1024) void scan2_kernel(int* __restrict__ blockSums, int nb)
{
    __shared__ int tmp[1024];
    int tid = threadIdx.x;
    int v = (tid < nb) ? blockSums[tid] : 0;
    tmp[tid] = v;
    __syncthreads();
#pragma unroll
    for (int off = 1; off < 1024; off <<= 1) {
        int t = (tid >= off) ? tmp[tid - off] : 0;
        __syncthreads();
        tmp[tid] += t;
        __syncthreads();
    }
    if (tid < nb) blockSums[tid] = tmp[tid] - v;  // exclusive
}

__global__ __launch_bounds__(256) void scan3_kernel(
    const int* __restrict__ vals, const int* __restrict__ blockSums,
    int* __restrict__ cscan, int M, int E)
{
    int i = blockIdx.x * 256 + threadIdx.x;
    if (i < M) {
        cscan[i] = cscan[i] - vals[i] + blockSums[i >> 8];
    }
    if (i == 0) cscan[M] = E;
}

__global__ __launch_bounds__(256) void csr_scatter_kernel(
    const int* __restrict__ src, const int* __restrict__ dst,
    const int* __restrict__ cscan, int* __restrict__ ebuf,
    int E, int TB, int NB)
{
    __shared__ int baseB[NB_MAX];
    __shared__ int cur[NB_MAX];
    int tid = threadIdx.x;
    int t = blockIdx.x;
    for (int b = tid; b < NB; b += 256) {
        baseB[b] = cscan[b * TB + t];
        cur[b] = 0;
    }
    __syncthreads();
    int base = t * TILE_E;
    for (int i = tid; i < TILE_E; i += 256) {
        int k = base + i;
        if (k < E) {
            int d = dst[k], s = src[k];
            int b = d >> 8;
            int r = atomicAdd(&cur[b], 1);
            ebuf[baseB[b] + r] = (s << 8) | (d & 255);
        }
    }
}

__global__ __launch_bounds__(256) void csr_bucket_kernel(
    const int* __restrict__ ebuf, const int* __restrict__ cscan,
    int* __restrict__ csr_src, int* __restrict__ offsets,
    int N, int E, int TB)
{
    __shared__ int eb[8192];      // 32KB staging
    __shared__ int hist[256];
    __shared__ int loff[256];
    __shared__ int tmp[256];
    int tid = threadIdx.x;
    int b = blockIdx.x;

    int beg = cscan[b * TB];
    int endv = cscan[(b + 1) * TB];
    int cnt = endv - beg;
    int first = b << 8;

    hist[tid] = 0;
    __syncthreads();

    bool inLds = (cnt <= 8192);
    for (int i = tid; i < cnt; i += 256) {
        int v = ebuf[beg + i];
        if (inLds) eb[i] = v;
        atomicAdd(&hist[v & 255], 1);
    }
    __syncthreads();

    int hv = hist[tid];
    tmp[tid] = hv;
    __syncthreads();
#pragma unroll
    for (int off = 1; off < 256; off <<= 1) {
        int t = (tid >= off) ? tmp[tid - off] : 0;
        __syncthreads();
        tmp[tid] += t;
        __syncthreads();
    }
    loff[tid] = tmp[tid] - hv;
    __syncthreads();

    if (first + tid < N) offsets[first + tid] = beg + loff[tid];
    if (b == 0 && tid == 0) offsets[N] = E;

    hist[tid] = 0;
    __syncthreads();

    for (int i = tid; i < cnt; i += 256) {
        int v = inLds ? eb[i] : ebuf[beg + i];
        int d8 = v & 255;
        int r = atomicAdd(&hist[d8], 1);
        csr_src[beg + loff[d8] + r] = v >> 8;
    }
}

// ============================================================================
// Gather core: fused softmax + weighted bf16 aggregation, one node per
// 32-lane group. Produces v = relu(sum(alpha*z)).
// ============================================================================

#define AGG32_CORE(S_SRC, S_DST, ZB)                                          \
    int beg = offsets[node], end = offsets[node + 1];                         \
    int deg = end - beg;                                                      \
    float sd = (S_DST)[node];                                                 \
    float o = 0.f;                                                            \
    float rden;                                                               \
    if (deg <= 128) {                                                         \
        int   sreg[4];                                                        \
        float ev[4];                                                          \
        int nIter = (deg + 31) >> 5;                                          \
        float m = -3.0e38f;                                                   \
        _Pragma("unroll 4")                                                   \
        for (int it = 0; it < nIter; ++it) {                                  \
            int p = beg + it * 32 + lane;                                     \
            float e = -3.0e38f;                                               \
            int s = 0;                                                        \
            if (p < end) {                                                    \
                s = csr_src[p];                                               \
                e = (S_SRC)[s] + sd;                                          \
                e = (e > 0.f) ? e : NEG_SLOPE * e;                            \
            }                                                                 \
            sreg[it] = s;                                                     \
            ev[it] = e;                                                       \
            m = fmaxf(m, e);                                                  \
        }                                                                     \
        _Pragma("unroll")                                                     \
        for (int off = 16; off > 0; off >>= 1)                                \
            m = fmaxf(m, __shfl_xor(m, off, 32));                             \
        float l = 0.f;                                                        \
        _Pragma("unroll 4")                                                   \
        for (int it = 0; it < nIter; ++it) {                                  \
            int p = beg + it * 32 + lane;                                     \
            float w = (p < end) ? __expf(ev[it] - m) : 0.f;                   \
            ws[it * 32 + lane] = make_float2(w, __int_as_float(sreg[it]));    \
            l += w;                                                           \
        }                                                                     \
        _Pragma("unroll")                                                     \
        for (int off = 16; off > 0; off >>= 1) l += __shfl_xor(l, off, 32);   \
        rden = 1.f / fmaxf(l, 1e-9f);                                         \
        int p = 0;                                                            \
        for (; p + 8 <= deg; p += 8) {                                        \
            float2 a0 = ws[p],     a1 = ws[p + 1];                            \
            float2 a2 = ws[p + 2], a3 = ws[p + 3];                            \
            float2 a4 = ws[p + 4], a5 = ws[p + 5];                            \
            float2 a6 = ws[p + 6], a7 = ws[p + 7];                            \
            unsigned short u0 = (ZB)[(size_t)__float_as_int(a0.y) * 32 + lane]; \
            unsigned short u1 = (ZB)[(size_t)__float_as_int(a1.y) * 32 + lane]; \
            unsigned short u2 = (ZB)[(size_t)__float_as_int(a2.y) * 32 + lane]; \
            unsigned short u3 = (ZB)[(size_t)__float_as_int(a3.y) * 32 + lane]; \
            unsigned short u4 = (ZB)[(size_t)__float_as_int(a4.y) * 32 + lane]; \
            unsigned short u5 = (ZB)[(size_t)__float_as_int(a5.y) * 32 + lane]; \
            unsigned short u6 = (ZB)[(size_t)__float_as_int(a6.y) * 32 + lane]; \
            unsigned short u7 = (ZB)[(size_t)__float_as_int(a7.y) * 32 + lane]; \
            o += a0.x * bf2f(u0); o += a1.x * bf2f(u1);                       \
            o += a2.x * bf2f(u2); o += a3.x * bf2f(u3);                       \
            o += a4.x * bf2f(u4); o += a5.x * bf2f(u5);                       \
            o += a6.x * bf2f(u6); o += a7.x * bf2f(u7);                       \
        }                                                                     \
        for (; p < deg; ++p) {                                                \
            float2 aa = ws[p];                                                \
            o += aa.x * bf2f((ZB)[(size_t)__float_as_int(aa.y) * 32 + lane]); \
        }                                                                     \
    } else {                                                                  \
        float m = -3.0e38f;                                                   \
        for (int p = beg + lane; p < end; p += 32) {                          \
            float e = (S_SRC)[csr_src[p]] + sd;                               \
            e = (e > 0.f) ? e : NEG_SLOPE * e;                                \
            m = fmaxf(m, e);                                                  \
        }                                                                     \
        _Pragma("unroll")                                                     \
        for (int off = 16; off > 0; off >>= 1)                                \
            m = fmaxf(m, __shfl_xor(m, off, 32));                             \
        float l = 0.f;                                                        \
        for (int p = beg + lane; p < end; p += 32) {                          \
            float e = (S_SRC)[csr_src[p]] + sd;                               \
            e = (e > 0.f) ? e : NEG_SLOPE * e;                                \
            l += __expf(e - m);                                               \
        }                                                                     \
        _Pragma("unroll")                                                     \
        for (int off = 16; off > 0; off >>= 1) l += __shfl_xor(l, off, 32);   \
        rden = 1.f / fmaxf(l, 1e-9f);                                         \
        for (int p = beg; p < end; ++p) {                                     \
            int s = csr_src[p];                                               \
            float e = (S_SRC)[s] + sd;                                        \
            e = (e > 0.f) ? e : NEG_SLOPE * e;                                \
            float w = __expf(e - m);                                          \
            o += w * bf2f((ZB)[(size_t)s * 32 + lane]);                       \
        }                                                                     \
    }                                                                         \
    float v = o * rden;                                                       \
    v = (v > 0.f) ? v : 0.f;   /* relu */

// ---- layer 1 agg, fused gemm2 epilogue. R13 lesson: do NOT hold W2 column
// in 32 VGPRs (occupancy 69->45%, net loss). Hybrid: h broadcast via LDS
// (1 ds_write + 8 ds_read_b128), W2 read per-k from LDS (32 conflict-free
// b32 feeding FMAs) -> 41 LDS ops/node vs 64 for the shfl matvec, no VGPR
// pressure. ----
__global__ __launch_bounds__(256) void agg32_l1_kernel(
    const int* __restrict__ offsets, const int* __restrict__ csr_src,
    const float* __restrict__ s_src1, const float* __restrict__ s_dst1,
    const unsigned short* __restrict__ zb1,
    const float* __restrict__ W2, const float* __restrict__ a2,
    unsigned short* __restrict__ zb2,
    float* __restrict__ s_src2, float* __restrict__ s_dst2, int N)
{
    __shared__ float W2l[32 * 32];      // 4 KB (stage once per block)
    __shared__ float2 wsbuf[8 * 128];   // 8 KB
    __shared__ float hl[8 * 32];        // 1 KB: per-group h row
    int tid = threadIdx.x;
    for (int i = tid; i < 1024; i += 256) W2l[i] = W2[i];
    __syncthreads();

    int g    = tid >> 5;
    int lane = tid & 31;
    int node = blockIdx.x * 8 + g;
    if (node >= N) return;
    float2* ws = &wsbuf[g * 128];

    AGG32_CORE(s_src1, s_dst1, zb1)

    // fused gemm2: z2[node][lane] = sum_k h1[k] * W2[k][lane]
    hl[g * 32 + lane] = v;              // intra-wave: no barrier needed
    const float4* hb4 = (const float4*)&hl[g * 32];
    float acc2 = 0.f;
#pragma unroll
    for (int c = 0; c < 8; ++c) {
        float4 hv = hb4[c];             // same-addr broadcast, conflict-free
        acc2 += hv.x * W2l[(c * 4 + 0) * 32 + lane];
        acc2 += hv.y * W2l[(c * 4 + 1) * 32 + lane];
        acc2 += hv.z * W2l[(c * 4 + 2) * 32 + lane];
        acc2 += hv.w * W2l[(c * 4 + 3) * 32 + lane];
    }

    zb2[(size_t)node * 32 + lane] = f2bf(acc2);
    float ps = acc2 * a2[lane];
    float pd = acc2 * a2[32 + lane];
#pragma unroll
    for (int off = 16; off > 0; off >>= 1) {
        ps += __shfl_xor(ps, off, 32);
        pd += __shfl_xor(pd, off, 32);
    }
    if (lane == 0) { s_src2[node] = ps; s_dst2[node] = pd; }
}

// ---- layer 2 agg, fused gemm3 epilogue: emits zs={z3,z3*a0}, s_dst3 ----
__global__ __launch_bounds__(256) void agg32_l2_kernel(
    const int* __restrict__ offsets, const int* __restrict__ csr_src,
    const float* __restrict__ s_src2, const float* __restrict__ s_dst2,
    const unsigned short* __restrict__ zb2,
    const float* __restrict__ W3, const float* __restrict__ a3,
    float2* __restrict__ zs, float* __restrict__ s_dst3, int N)
{
    __shared__ float2 wsbuf[8 * 128];
    int tid  = threadIdx.x;
    int g    = tid >> 5;
    int lane = tid & 31;
    int node = blockIdx.x * 8 + g;
    if (node >= N) return;
    float2* ws = &wsbuf[g * 128];
    float w3 = W3[lane];

    AGG32_CORE(s_src2, s_dst2, zb2)

    // fused gemm3: z3 = sum_lane h2[lane] * W3[lane]
    float t = v * w3;
#pragma unroll
    for (int off = 16; off > 0; off >>= 1) t += __shfl_xor(t, off, 32);
    if (lane == 0) {
        zs[node] = make_float2(t, t * a3[0]);
        s_dst3[node] = t * a3[1];
    }
}

// ---- layer 3: fully edge-parallel, one 8B fp32 gather per edge, sigmoid ----
__global__ __launch_bounds__(256) void agg1_fused_kernel(
    const int* __restrict__ offsets, const int* __restrict__ csr_src,
    const float2* __restrict__ zs, const float* __restrict__ s_dst,
    float* __restrict__ out, int N)
{
    int node = blockIdx.x * 8 + (threadIdx.x >> 5);
    int lane = threadIdx.x & 31;
    if (node >= N) return;

    int beg = offsets[node], end = offsets[node + 1];
    int deg = end - beg;
    float sd = s_dst[node];

    if (deg <= 128) {
        float ev[4], zv[4];
        int nIter = (deg + 31) >> 5;
        float m = -3.0e38f;
#pragma unroll 4
        for (int it = 0; it < nIter; ++it) {
            int p = beg + it * 32 + lane;
            float e = -3.0e38f, zz = 0.f;
            if (p < end) {
                float2 v2 = zs[csr_src[p]];
                zz = v2.x;
                e = v2.y + sd;
                e = (e > 0.f) ? e : NEG_SLOPE * e;
            }
            ev[it] = e; zv[it] = zz;
            m = fmaxf(m, e);
        }
#pragma unroll
        for (int off = 16; off > 0; off >>= 1) m = fmaxf(m, __shfl_xor(m, off, 32));
        float l = 0.f, o = 0.f;
#pragma unroll 4
        for (int it = 0; it < nIter; ++it) {
            int p = beg + it * 32 + lane;
            float w = (p < end) ? __expf(ev[it] - m) : 0.f;
            l += w;
            o += w * zv[it];
        }
#pragma unroll
        for (int off = 16; off > 0; off >>= 1) {
            l += __shfl_xor(l, off, 32);
            o += __shfl_xor(o, off, 32);
        }
        if (lane == 0) {
            float v = o / fmaxf(l, 1e-9f);
            out[node] = 1.f / (1.f + __expf(-v));
        }
    } else {
        float m = -3.0e38f;
        for (int p = beg + lane; p < end; p += 32) {
            float e = zs[csr_src[p]].y + sd;
            e = (e > 0.f) ? e : NEG_SLOPE * e;
            m = fmaxf(m, e);
        }
#pragma unroll
        for (int off = 16; off > 0; off >>= 1) m = fmaxf(m, __shfl_xor(m, off, 32));
        float l = 0.f, o = 0.f;
        for (int p = beg + lane; p < end; p += 32) {
            float2 v2 = zs[csr_src[p]];
            float e = v2.y + sd;
            e = (e > 0.f) ? e : NEG_SLOPE * e;
            float w = __expf(e - m);
            l += w; o += w * v2.x;
        }
#pragma unroll
        for (int off = 16; off > 0; off >>= 1) {
            l += __shfl_xor(l, off, 32);
            o += __shfl_xor(o, off, 32);
        }
        if (lane == 0) {
            float v = o / fmaxf(l, 1e-9f);
            out[node] = 1.f / (1.f + __expf(-v));
        }
    }
}

// ============================================================================

extern "C" void kernel_launch(void* const* d_in, const int* in_sizes, int n_in,
                              void* d_out, int out_size, void* d_ws, size_t ws_size,
                              hipStream_t stream)
{
    const float* feature = (const float*)d_in[0];
    const int*   src     = (const int*)d_in[1];
    const int*   dst     = (const int*)d_in[2];
    const float* W1      = (const float*)d_in[3];
    const float* a1      = (const float*)d_in[4];
    const float* W2      = (const float*)d_in[5];
    const float* a2      = (const float*)d_in[6];
    const float* W3      = (const float*)d_in[7];
    const float* a3      = (const float*)d_in[8];
    float* out = (float*)d_out;

    const int N = in_sizes[0] / 128;
    const int E = in_sizes[1];

    const int TB = (E + TILE_E - 1) / TILE_E;
    const int NB = (N + 255) >> 8;
    const int M  = NB * TB;

    // ---- workspace layout ----
    char* p = (char*)d_ws;
    unsigned short* zb1 = (unsigned short*)p;  p += (size_t)N * 32 * sizeof(unsigned short);
    unsigned short* zb2 = (unsigned short*)p;  p += (size_t)N * 32 * sizeof(unsigned short);
    float* zs32    = (float*)p;  p += (size_t)N * 2 * sizeof(float);
    float* s_src1  = (float*)p;  p += (size_t)N * sizeof(float);
    float* s_dst1  = (float*)p;  p += (size_t)N * sizeof(float);
    float* s_src2  = (float*)p;  p += (size_t)N * sizeof(float);
    float* s_dst2  = (float*)p;  p += (size_t)N * sizeof(float);
    float* s_dst3  = (float*)p;  p += (size_t)N * sizeof(float);
    int*   offsets = (int*)p;    p += ((size_t)N + 1) * sizeof(int);
    int*   counts  = (int*)p;    p += ((size_t)M + 1) * sizeof(int);
    int*   cscan   = (int*)p;    p += ((size_t)M + 1) * sizeof(int);
    int*   blockSums = (int*)p;  p += 1024 * sizeof(int);
    int*   ebuf    = (int*)p;    p += (size_t)E * sizeof(int);
    int*   csr_src = (int*)p;    p += (size_t)E * sizeof(int);

    const int nodeBlocks8  = (N + 7) / 8;
    const int gemmBlocks64 = (N + 63) / 64;
    const int scanBlocksM  = (M + 255) / 256;

    // ---- build CSR: atomic-free two-level counting sort ----
    hipLaunchKernelGGL(csr_hist_kernel, dim3(TB), dim3(256), 0, stream,
                       dst, counts, E, TB, NB);
    hipLaunchKernelGGL(scan1_kernel, dim3(scanBlocksM), dim3(256), 0, stream,
                       counts, cscan, blockSums, M);
    hipLaunchKernelGGL(scan2_kernel, dim3(1), dim3(1024), 0, stream,
                       blockSums, scanBlocksM);
    hipLaunchKernelGGL(scan3_kernel, dim3(scanBlocksM), dim3(256), 0, stream,
                       counts, blockSums, cscan, M, E);
    hipLaunchKernelGGL(csr_scatter_kernel, dim3(TB), dim3(256), 0, stream,
                       src, dst, cscan, ebuf, E, TB, NB);
    hipLaunchKernelGGL(csr_bucket_kernel, dim3(NB), dim3(256), 0, stream,
                       ebuf, cscan, csr_src, offsets, N, E, TB);

    // ---- layer 1: gemm1 -> z1; agg(l1) fused with gemm2 -> z2 ----
    hipLaunchKernelGGL(gemm1_kernel, dim3(gemmBlocks64), dim3(128), 0, stream,
                       feature, W1, a1, zb1, s_src1, s_dst1, N);
    hipLaunchKernelGGL(agg32_l1_kernel, dim3(nodeBlocks8), dim3(256), 0, stream,
                       offsets, csr_src, s_src1, s_dst1, zb1, W2, a2,
                       zb2, s_src2, s_dst2, N);

    // ---- layer 2: agg(l2) fused with gemm3 -> zs, s_dst3 ----
    float2* zs = (float2*)zs32;
    hipLaunchKernelGGL(agg32_l2_kernel, dim3(nodeBlocks8), dim3(256), 0, stream,
                       offsets, csr_src, s_src2, s_dst2, zb2, W3, a3,
                       zs, s_dst3, N);

    // ---- layer 3: edge-parallel agg + sigmoid ----
    hipLaunchKernelGGL(agg1_fused_kernel, dim3(nodeBlocks8), dim3(256), 0, stream,
                       offsets, csr_src, zs, s_dst3, out, N);
}

// Round 15
// 261.743 us; speedup vs baseline: 1.0765x; 1.0189x over previous
//
#include <hip/hip_runtime.h>
#include <hip/hip_bf16.h>
#include <cstdint>
#include <cstddef>

#define NEG_SLOPE 0.01f

static __device__ __forceinline__ unsigned short f2bf(float f) {
    __hip_bfloat16 b = __float2bfloat16(f);   // RNE
    return *(unsigned short*)&b;
}

// ============================================================================
// Layer-1 GEMM: z1 = feature[N,128] @ W1[128,32] (bf16 out) + fp32 logits.
// ============================================================================

__global__ __launch_bounds__(128) void gemm1_kernel(
    const float* __restrict__ h, const float* __restrict__ W,
    const float* __restrict__ a, unsigned short* __restrict__ zb,
    float* __restrict__ s_src, float* __restrict__ s_dst, int N)
{
    __shared__ float Wl[128 * 32];
    int tid = threadIdx.x;
    int rowBase = blockIdx.x * 64;

    {
        const float4* W4 = (const float4*)W;
        float4* Wl4 = (float4*)Wl;
        for (int i = tid; i < 1024; i += 128) Wl4[i] = W4[i];
    }
    __syncthreads();

    int wv   = tid >> 6;
    int lane = tid & 63;
    int g    = lane >> 3;
    int l8   = lane & 7;
    int r0   = wv * 32 + g * 4;
    int col4 = l8 * 4;

    float acc[4][4];
#pragma unroll
    for (int i = 0; i < 4; i++)
#pragma unroll
        for (int c = 0; c < 4; c++) acc[i][c] = 0.f;

    const float4* h4  = (const float4*)h;
    const float4* Wl4 = (const float4*)Wl;

    size_t rowOff[4];
#pragma unroll
    for (int i = 0; i < 4; i++) {
        int r = rowBase + r0 + i;
        rowOff[i] = (size_t)((r < N) ? r : (N - 1)) * 32;
    }

#pragma unroll 2
    for (int kq = 0; kq < 32; kq++) {
        float4 w0 = Wl4[(kq * 4 + 0) * 8 + l8];
        float4 w1 = Wl4[(kq * 4 + 1) * 8 + l8];
        float4 w2 = Wl4[(kq * 4 + 2) * 8 + l8];
        float4 w3 = Wl4[(kq * 4 + 3) * 8 + l8];
#pragma unroll
        for (int i = 0; i < 4; i++) {
            float4 hv = h4[rowOff[i] + kq];
            acc[i][0] += hv.x * w0.x; acc[i][1] += hv.x * w0.y;
            acc[i][2] += hv.x * w0.z; acc[i][3] += hv.x * w0.w;
            acc[i][0] += hv.y * w1.x; acc[i][1] += hv.y * w1.y;
            acc[i][2] += hv.y * w1.z; acc[i][3] += hv.y * w1.w;
            acc[i][0] += hv.z * w2.x; acc[i][1] += hv.z * w2.y;
            acc[i][2] += hv.z * w2.z; acc[i][3] += hv.z * w2.w;
            acc[i][0] += hv.w * w3.x; acc[i][1] += hv.w * w3.y;
            acc[i][2] += hv.w * w3.z; acc[i][3] += hv.w * w3.w;
        }
    }

    float4 alo = ((const float4*)a)[l8];
    float4 ahi = ((const float4*)a)[8 + l8];
#pragma unroll
    for (int i = 0; i < 4; i++) {
        int row = rowBase + r0 + i;
        if (row < N) {
            ushort4 zv4 = make_ushort4(f2bf(acc[i][0]), f2bf(acc[i][1]),
                                       f2bf(acc[i][2]), f2bf(acc[i][3]));
            *(ushort4*)&zb[(size_t)row * 32 + col4] = zv4;
            float ps = acc[i][0] * alo.x + acc[i][1] * alo.y + acc[i][2] * alo.z + acc[i][3] * alo.w;
            float pd = acc[i][0] * ahi.x + acc[i][1] * ahi.y + acc[i][2] * ahi.z + acc[i][3] * ahi.w;
            ps += __shfl_xor(ps, 1, 64); ps += __shfl_xor(ps, 2, 64); ps += __shfl_xor(ps, 4, 64);
            pd += __shfl_xor(pd, 1, 64); pd += __shfl_xor(pd, 2, 64); pd += __shfl_xor(pd, 4, 64);
            if (l8 == 0) { s_src[row] = ps; s_dst[row] = pd; }
        }
    }
}

// ============================================================================
// Atomic-free CSR build: two-level counting sort by dst (LDS atomics only).
// ============================================================================

#define TILE_E 4096
#define NB_MAX 512     // supports N <= 131072

__global__ __launch_bounds__(256) void csr_hist_kernel(
    const int* __restrict__ dst, int* __restrict__ counts,
    int E, int TB, int NB)
{
    __shared__ int hist[NB_MAX];
    int tid = threadIdx.x;
    int t = blockIdx.x;
    for (int b = tid; b < NB; b += 256) hist[b] = 0;
    __syncthreads();
    int base = t * TILE_E;
    for (int i = tid; i < TILE_E; i += 256) {
        int k = base + i;
        if (k < E) atomicAdd(&hist[dst[k] >> 8], 1);
    }
    __syncthreads();
    for (int b = tid; b < NB; b += 256) counts[b * TB + t] = hist[b];
}

__global__ __launch_bounds__(256) void scan1_kernel(
    const int* __restrict__ vals, int* __restrict__ incl,
    int* __restrict__ blockSums, int M)
{
    __shared__ int tmp[256];
    int tid = threadIdx.x;
    int i = blockIdx.x * 256 + tid;
    int v = (i < M) ? vals[i] : 0;
    tmp[tid] = v;
    __syncthreads();
#pragma unroll
    for (int off = 1; off < 256; off <<= 1) {
        int t = (tid >= off) ? tmp[tid - off] : 0;
        __syncthreads();
        tmp[tid] += t;
        __syncthreads();
    }
    if (i < M) incl[i] = tmp[tid];
    if (tid == 255) blockSums[blockIdx.x] = tmp[255];
}

__global__ __launch_bounds__(1024) void scan2_kernel(int* __restrict__ blockSums, int nb)
{
    __shared__ int tmp[1024];
    int tid = threadIdx.x;
    int v = (tid < nb) ? blockSums[tid] : 0;
    tmp[tid] = v;
    __syncthreads();
#pragma unroll
    for (int off = 1; off < 1024; off <<= 1) {
        int t = (tid >= off) ? tmp[tid - off] : 0;
        __syncthreads();
        tmp[tid] += t;
        __syncthreads();
    }
    if (tid < nb) blockSums[tid] = tmp[tid] - v;  // exclusive
}

__global__ __launch_bounds__(256) void scan3_kernel(
    const int* __restrict__ vals, const int* __restrict__ blockSums,
    int* __restrict__ cscan, int M, int E)
{
    int i = blockIdx.x * 256 + threadIdx.x;
    if (i < M) {
        cscan[i] = cscan[i] - vals[i] + blockSums[i >> 8];
    }
    if (i == 0) cscan[M] = E;
}

__global__ __launch_bounds__(256) void csr_scatter_kernel(
    const int* __restrict__ src, const int* __restrict__ dst,
    const int* __restrict__ cscan, int* __restrict__ ebuf,
    int E, int TB, int NB)
{
    __shared__ int baseB[NB_MAX];
    __shared__ int cur[NB_MAX];
    int tid = threadIdx.x;
    int t = blockIdx.x;
    for (int b = tid; b < NB; b += 256) {
        baseB[b] = cscan[b * TB + t];
        cur[b] = 0;
    }
    __syncthreads();
    int base = t * TILE_E;
    for (int i = tid; i < TILE_E; i += 256) {
        int k = base + i;
        if (k < E) {
            int d = dst[k], s = src[k];
            int b = d >> 8;
            int r = atomicAdd(&cur[b], 1);
            ebuf[baseB[b] + r] = (s << 8) | (d & 255);
        }
    }
}

__global__ __launch_bounds__(256) void csr_bucket_kernel(
    const int* __restrict__ ebuf, const int* __restrict__ cscan,
    int* __restrict__ csr_src, int* __restrict__ offsets,
    int N, int E, int TB)
{
    __shared__ int eb[8192];      // 32KB staging
    __shared__ int hist[256];
    __shared__ int loff[256];
    __shared__ int tmp[256];
    int tid = threadIdx.x;
    int b = blockIdx.x;

    int beg = cscan[b * TB];
    int endv = cscan[(b + 1) * TB];
    int cnt = endv - beg;
    int first = b << 8;

    hist[tid] = 0;
    __syncthreads();

    bool inLds = (cnt <= 8192);
    for (int i = tid; i < cnt; i += 256) {
        int v = ebuf[beg + i];
        if (inLds) eb[i] = v;
        atomicAdd(&hist[v & 255], 1);
    }
    __syncthreads();

    int hv = hist[tid];
    tmp[tid] = hv;
    __syncthreads();
#pragma unroll
    for (int off = 1; off < 256; off <<= 1) {
        int t = (tid >= off) ? tmp[tid - off] : 0;
        __syncthreads();
        tmp[tid] += t;
        __syncthreads();
    }
    loff[tid] = tmp[tid] - hv;
    __syncthreads();

    if (first + tid < N) offsets[first + tid] = beg + loff[tid];
    if (b == 0 && tid == 0) offsets[N] = E;

    hist[tid] = 0;
    __syncthreads();

    for (int i = tid; i < cnt; i += 256) {
        int v = inLds ? eb[i] : ebuf[beg + i];
        int d8 = v & 255;
        int r = atomicAdd(&hist[d8], 1);
        csr_src[beg + loff[d8] + r] = v >> 8;
    }
}

// ============================================================================
// Gather core: fused softmax + weighted bf16 aggregation, one node per
// 32-lane group. R15: phase B processes 2 EDGES per iteration — lanes split
// into 16-lane halves (half = lane>>4), each lane owns a COLUMN PAIR
// (cols 2c,2c+1, c=lane&15) loaded as one packed uint (2 bf16). Halves the
// ws reads + gathers per edge; bf16->f32 via shift/mask (cheaper than cvt).
// Phase A already zero-fills ws up to nIter*32, so odd-deg needs no padding.
// Produces vv = float2 of relu'd, normalized output for cols {2c, 2c+1},
// valid on ALL 32 lanes (halves combined via shfl_xor 16).
// ============================================================================

#define AGG32_CORE(S_SRC, S_DST, ZB)                                          \
    int beg = offsets[node], end = offsets[node + 1];                         \
    int deg = end - beg;                                                      \
    float sd = (S_DST)[node];                                                 \
    int half = lane >> 4;                                                     \
    int cp   = (lane & 15) * 2;                                               \
    float2 o2 = make_float2(0.f, 0.f);                                        \
    float rden;                                                               \
    if (deg <= 128) {                                                         \
        int   sreg[4];                                                        \
        float ev[4];                                                          \
        int nIter = (deg + 31) >> 5;                                          \
        float m = -3.0e38f;                                                   \
        _Pragma("unroll 4")                                                   \
        for (int it = 0; it < nIter; ++it) {                                  \
            int p = beg + it * 32 + lane;                                     \
            float e = -3.0e38f;                                               \
            int s = 0;                                                        \
            if (p < end) {                                                    \
                s = csr_src[p];                                               \
                e = (S_SRC)[s] + sd;                                          \
                e = (e > 0.f) ? e : NEG_SLOPE * e;                            \
            }                                                                 \
            sreg[it] = s;                                                     \
            ev[it] = e;                                                       \
            m = fmaxf(m, e);                                                  \
        }                                                                     \
        _Pragma("unroll")                                                     \
        for (int off = 16; off > 0; off >>= 1)                                \
            m = fmaxf(m, __shfl_xor(m, off, 32));                             \
        float l = 0.f;                                                        \
        _Pragma("unroll 4")                                                   \
        for (int it = 0; it < nIter; ++it) {                                  \
            int p = beg + it * 32 + lane;                                     \
            float w = (p < end) ? __expf(ev[it] - m) : 0.f;                   \
            ws[it * 32 + lane] = make_float2(w, __int_as_float(sreg[it]));    \
            l += w;                                                           \
        }                                                                     \
        _Pragma("unroll")                                                     \
        for (int off = 16; off > 0; off >>= 1) l += __shfl_xor(l, off, 32);   \
        rden = 1.f / fmaxf(l, 1e-9f);                                         \
        int degP = (deg + 1) & ~1;                                            \
        int p = 0;                                                            \
        for (; p + 8 <= degP; p += 8) {                                       \
            float2 a0 = ws[p +     half], a1 = ws[p + 2 + half];              \
            float2 a2 = ws[p + 4 + half], a3 = ws[p + 6 + half];              \
            unsigned u0 = *(const unsigned*)((ZB) + (size_t)__float_as_int(a0.y) * 32 + cp); \
            unsigned u1 = *(const unsigned*)((ZB) + (size_t)__float_as_int(a1.y) * 32 + cp); \
            unsigned u2 = *(const unsigned*)((ZB) + (size_t)__float_as_int(a2.y) * 32 + cp); \
            unsigned u3 = *(const unsigned*)((ZB) + (size_t)__float_as_int(a3.y) * 32 + cp); \
            o2.x += a0.x * __uint_as_float(u0 << 16);                         \
            o2.y += a0.x * __uint_as_float(u0 & 0xffff0000u);                 \
            o2.x += a1.x * __uint_as_float(u1 << 16);                         \
            o2.y += a1.x * __uint_as_float(u1 & 0xffff0000u);                 \
            o2.x += a2.x * __uint_as_float(u2 << 16);                         \
            o2.y += a2.x * __uint_as_float(u2 & 0xffff0000u);                 \
            o2.x += a3.x * __uint_as_float(u3 << 16);                         \
            o2.y += a3.x * __uint_as_float(u3 & 0xffff0000u);                 \
        }                                                                     \
        for (; p < degP; p += 2) {                                            \
            float2 aa = ws[p + half];                                         \
            unsigned u = *(const unsigned*)((ZB) + (size_t)__float_as_int(aa.y) * 32 + cp); \
            o2.x += aa.x * __uint_as_float(u << 16);                          \
            o2.y += aa.x * __uint_as_float(u & 0xffff0000u);                  \
        }                                                                     \
    } else {                                                                  \
        float m = -3.0e38f;                                                   \
        for (int p = beg + lane; p < end; p += 32) {                          \
            float e = (S_SRC)[csr_src[p]] + sd;                               \
            e = (e > 0.f) ? e : NEG_SLOPE * e;                                \
            m = fmaxf(m, e);                                                  \
        }                                                                     \
        _Pragma("unroll")                                                     \
        for (int off = 16; off > 0; off >>= 1)                                \
            m = fmaxf(m, __shfl_xor(m, off, 32));                             \
        float l = 0.f;                                                        \
        for (int p = beg + lane; p < end; p += 32) {                          \
            float e = (S_SRC)[csr_src[p]] + sd;                               \
            e = (e > 0.f) ? e : NEG_SLOPE * e;                                \
            l += __expf(e - m);                                               \
        }                                                                     \
        _Pragma("unroll")                                                     \
        for (int off = 16; off > 0; off >>= 1) l += __shfl_xor(l, off, 32);   \
        rden = 1.f / fmaxf(l, 1e-9f);                                         \
        for (int p = 0; p < deg; p += 2) {                                    \
            int idx = p + half;                                               \
            int valid = (idx < deg);                                          \
            int s = csr_src[beg + (valid ? idx : deg - 1)];                   \
            float e = (S_SRC)[s] + sd;                                        \
            e = (e > 0.f) ? e : NEG_SLOPE * e;                                \
            float w = valid ? __expf(e - m) : 0.f;                            \
            unsigned u = *(const unsigned*)((ZB) + (size_t)s * 32 + cp);      \
            o2.x += w * __uint_as_float(u << 16);                             \
            o2.y += w * __uint_as_float(u & 0xffff0000u);                     \
        }                                                                     \
    }                                                                         \
    o2.x += __shfl_xor(o2.x, 16, 32);                                         \
    o2.y += __shfl_xor(o2.y, 16, 32);                                         \
    float2 vv;                                                                \
    vv.x = o2.x * rden; vv.x = (vv.x > 0.f) ? vv.x : 0.f;                     \
    vv.y = o2.y * rden; vv.y = (vv.y > 0.f) ? vv.y : 0.f;

// ---- layer 1 agg, fused gemm2 epilogue (hybrid LDS matvec — R14) ----
__global__ __launch_bounds__(256) void agg32_l1_kernel(
    const int* __restrict__ offsets, const int* __restrict__ csr_src,
    const float* __restrict__ s_src1, const float* __restrict__ s_dst1,
    const unsigned short* __restrict__ zb1,
    const float* __restrict__ W2, const float* __restrict__ a2,
    unsigned short* __restrict__ zb2,
    float* __restrict__ s_src2, float* __restrict__ s_dst2, int N)
{
    __shared__ float W2l[32 * 32];      // 4 KB (stage once per block)
    __shared__ float2 wsbuf[8 * 128];   // 8 KB
    __shared__ float hl[8 * 32];        // 1 KB: per-group h row
    int tid = threadIdx.x;
    for (int i = tid; i < 1024; i += 256) W2l[i] = W2[i];
    __syncthreads();

    int g    = tid >> 5;
    int lane = tid & 31;
    int node = blockIdx.x * 8 + g;
    if (node >= N) return;
    float2* ws = &wsbuf[g * 128];

    AGG32_CORE(s_src1, s_dst1, zb1)

    // stage h row: lanes<16 hold the col-pair values
    if (half == 0) *(float2*)&hl[g * 32 + cp] = vv;   // intra-wave ordering
    const float4* hb4 = (const float4*)&hl[g * 32];
    float acc2 = 0.f;
#pragma unroll
    for (int c = 0; c < 8; ++c) {
        float4 hv = hb4[c];             // same-addr broadcast, conflict-free
        acc2 += hv.x * W2l[(c * 4 + 0) * 32 + lane];
        acc2 += hv.y * W2l[(c * 4 + 1) * 32 + lane];
        acc2 += hv.z * W2l[(c * 4 + 2) * 32 + lane];
        acc2 += hv.w * W2l[(c * 4 + 3) * 32 + lane];
    }

    zb2[(size_t)node * 32 + lane] = f2bf(acc2);
    float ps = acc2 * a2[lane];
    float pd = acc2 * a2[32 + lane];
#pragma unroll
    for (int off = 16; off > 0; off >>= 1) {
        ps += __shfl_xor(ps, off, 32);
        pd += __shfl_xor(pd, off, 32);
    }
    if (lane == 0) { s_src2[node] = ps; s_dst2[node] = pd; }
}

// ---- layer 2 agg, fused gemm3 epilogue: emits zs={z3,z3*a0}, s_dst3 ----
__global__ __launch_bounds__(256) void agg32_l2_kernel(
    const int* __restrict__ offsets, const int* __restrict__ csr_src,
    const float* __restrict__ s_src2, const float* __restrict__ s_dst2,
    const unsigned short* __restrict__ zb2,
    const float* __restrict__ W3, const float* __restrict__ a3,
    float2* __restrict__ zs, float* __restrict__ s_dst3, int N)
{
    __shared__ float2 wsbuf[8 * 128];
    int tid  = threadIdx.x;
    int g    = tid >> 5;
    int lane = tid & 31;
    int node = blockIdx.x * 8 + g;
    if (node >= N) return;
    float2* ws = &wsbuf[g * 128];

    AGG32_CORE(s_src2, s_dst2, zb2)

    // fused gemm3: z3 = sum over cols of h2 * W3 (lane holds col pair)
    float2 w3p = ((const float2*)W3)[lane & 15];
    float t = vv.x * w3p.x + vv.y * w3p.y;
    t += __shfl_xor(t, 1, 32);
    t += __shfl_xor(t, 2, 32);
    t += __shfl_xor(t, 4, 32);
    t += __shfl_xor(t, 8, 32);   // halves are duplicates; 16-lane sum = total
    if (lane == 0) {
        zs[node] = make_float2(t, t * a3[0]);
        s_dst3[node] = t * a3[1];
    }
}

// ---- layer 3: fully edge-parallel, one 8B fp32 gather per edge, sigmoid ----
__global__ __launch_bounds__(256) void agg1_fused_kernel(
    const int* __restrict__ offsets, const int* __restrict__ csr_src,
    const float2* __restrict__ zs, const float* __restrict__ s_dst,
    float* __restrict__ out, int N)
{
    int node = blockIdx.x * 8 + (threadIdx.x >> 5);
    int lane = threadIdx.x & 31;
    if (node >= N) return;

    int beg = offsets[node], end = offsets[node + 1];
    int deg = end - beg;
    float sd = s_dst[node];

    if (deg <= 128) {
        float ev[4], zv[4];
        int nIter = (deg + 31) >> 5;
        float m = -3.0e38f;
#pragma unroll 4
        for (int it = 0; it < nIter; ++it) {
            int p = beg + it * 32 + lane;
            float e = -3.0e38f, zz = 0.f;
            if (p < end) {
                float2 v2 = zs[csr_src[p]];
                zz = v2.x;
                e = v2.y + sd;
                e = (e > 0.f) ? e : NEG_SLOPE * e;
            }
            ev[it] = e; zv[it] = zz;
            m = fmaxf(m, e);
        }
#pragma unroll
        for (int off = 16; off > 0; off >>= 1) m = fmaxf(m, __shfl_xor(m, off, 32));
        float l = 0.f, o = 0.f;
#pragma unroll 4
        for (int it = 0; it < nIter; ++it) {
            int p = beg + it * 32 + lane;
            float w = (p < end) ? __expf(ev[it] - m) : 0.f;
            l += w;
            o += w * zv[it];
        }
#pragma unroll
        for (int off = 16; off > 0; off >>= 1) {
            l += __shfl_xor(l, off, 32);
            o += __shfl_xor(o, off, 32);
        }
        if (lane == 0) {
            float v = o / fmaxf(l, 1e-9f);
            out[node] = 1.f / (1.f + __expf(-v));
        }
    } else {
        float m = -3.0e38f;
        for (int p = beg + lane; p < end; p += 32) {
            float e = zs[csr_src[p]].y + sd;
            e = (e > 0.f) ? e : NEG_SLOPE * e;
            m = fmaxf(m, e);
        }
#pragma unroll
        for (int off = 16; off > 0; off >>= 1) m = fmaxf(m, __shfl_xor(m, off, 32));
        float l = 0.f, o = 0.f;
        for (int p = beg + lane; p < end; p += 32) {
            float2 v2 = zs[csr_src[p]];
            float e = v2.y + sd;
            e = (e > 0.f) ? e : NEG_SLOPE * e;
            float w = __expf(e - m);
            l += w; o += w * v2.x;
        }
#pragma unroll
        for (int off = 16; off > 0; off >>= 1) {
            l += __shfl_xor(l, off, 32);
            o += __shfl_xor(o, off, 32);
        }
        if (lane == 0) {
            float v = o / fmaxf(l, 1e-9f);
            out[node] = 1.f / (1.f + __expf(-v));
        }
    }
}

// ============================================================================

extern "C" void kernel_launch(void* const* d_in, const int* in_sizes, int n_in,
                              void* d_out, int out_size, void* d_ws, size_t ws_size,
                              hipStream_t stream)
{
    const float* feature = (const float*)d_in[0];
    const int*   src     = (const int*)d_in[1];
    const int*   dst     = (const int*)d_in[2];
    const float* W1      = (const float*)d_in[3];
    const float* a1      = (const float*)d_in[4];
    const float* W2      = (const float*)d_in[5];
    const float* a2      = (const float*)d_in[6];
    const float* W3      = (const float*)d_in[7];
    const float* a3      = (const float*)d_in[8];
    float* out = (float*)d_out;

    const int N = in_sizes[0] / 128;
    const int E = in_sizes[1];

    const int TB = (E + TILE_E - 1) / TILE_E;
    const int NB = (N + 255) >> 8;
    const int M  = NB * TB;

    // ---- workspace layout ----
    char* p = (char*)d_ws;
    unsigned short* zb1 = (unsigned short*)p;  p += (size_t)N * 32 * sizeof(unsigned short);
    unsigned short* zb2 = (unsigned short*)p;  p += (size_t)N * 32 * sizeof(unsigned short);
    float* zs32    = (float*)p;  p += (size_t)N * 2 * sizeof(float);
    float* s_src1  = (float*)p;  p += (size_t)N * sizeof(float);
    float* s_dst1  = (float*)p;  p += (size_t)N * sizeof(float);
    float* s_src2  = (float*)p;  p += (size_t)N * sizeof(float);
    float* s_dst2  = (float*)p;  p += (size_t)N * sizeof(float);
    float* s_dst3  = (float*)p;  p += (size_t)N * sizeof(float);
    int*   offsets = (int*)p;    p += ((size_t)N + 1) * sizeof(int);
    int*   counts  = (int*)p;    p += ((size_t)M + 1) * sizeof(int);
    int*   cscan   = (int*)p;    p += ((size_t)M + 1) * sizeof(int);
    int*   blockSums = (int*)p;  p += 1024 * sizeof(int);
    int*   ebuf    = (int*)p;    p += (size_t)E * sizeof(int);
    int*   csr_src = (int*)p;    p += (size_t)E * sizeof(int);

    const int nodeBlocks8  = (N + 7) / 8;
    const int gemmBlocks64 = (N + 63) / 64;
    const int scanBlocksM  = (M + 255) / 256;

    // ---- build CSR: atomic-free two-level counting sort ----
    hipLaunchKernelGGL(csr_hist_kernel, dim3(TB), dim3(256), 0, stream,
                       dst, counts, E, TB, NB);
    hipLaunchKernelGGL(scan1_kernel, dim3(scanBlocksM), dim3(256), 0, stream,
                       counts, cscan, blockSums, M);
    hipLaunchKernelGGL(scan2_kernel, dim3(1), dim3(1024), 0, stream,
                       blockSums, scanBlocksM);
    hipLaunchKernelGGL(scan3_kernel, dim3(scanBlocksM), dim3(256), 0, stream,
                       counts, blockSums, cscan, M, E);
    hipLaunchKernelGGL(csr_scatter_kernel, dim3(TB), dim3(256), 0, stream,
                       src, dst, cscan, ebuf, E, TB, NB);
    hipLaunchKernelGGL(csr_bucket_kernel, dim3(NB), dim3(256), 0, stream,
                       ebuf, cscan, csr_src, offsets, N, E, TB);

    // ---- layer 1: gemm1 -> z1; agg(l1) fused with gemm2 -> z2 ----
    hipLaunchKernelGGL(gemm1_kernel, dim3(gemmBlocks64), dim3(128), 0, stream,
                       feature, W1, a1, zb1, s_src1, s_dst1, N);
    hipLaunchKernelGGL(agg32_l1_kernel, dim3(nodeBlocks8), dim3(256), 0, stream,
                       offsets, csr_src, s_src1, s_dst1, zb1, W2, a2,
                       zb2, s_src2, s_dst2, N);

    // ---- layer 2: agg(l2) fused with gemm3 -> zs, s_dst3 ----
    float2* zs = (float2*)zs32;
    hipLaunchKernelGGL(agg32_l2_kernel, dim3(nodeBlocks8), dim3(256), 0, stream,
                       offsets, csr_src, s_src2, s_dst2, zb2, W3, a3,
                       zs, s_dst3, N);

    // ---- layer 3: edge-parallel agg + sigmoid ----
    hipLaunchKernelGGL(agg1_fused_kernel, dim3(nodeBlocks8), dim3(256), 0, stream,
                       offsets, csr_src, zs, s_dst3, out, N);
}